// Round 5
// baseline (762.837 us; speedup 1.0000x reference)
//
#include <hip/hip_runtime.h>
#include <math.h>

#define KCLS 21
#define BATCH 16
#define HF 41
#define WF 41
#define HH 321
#define WW 321
#define CFEAT 2048
#define HWF (HF*WF)            // 1681
#define HWI (HH*WW)            // 103041
#define NPIX (BATCH*HWI)       // 1648656
#define NBLK_C ((NPIX + 255)/256)  // 6441
#define EPSC 1e-6f

__device__ float g_corr[(size_t)BATCH*KCLS*HWF];
__device__ float g_acc[6];
__device__ unsigned g_ticket;

// ---------------- kernel B: corr map at 41x41 (+ fused weight norms) ----
// grid (27, 16), block 512 (8 waves). 64 pixels/block (one per lane of each
// wave), C split into 8 wave-chunks of 256; chunk id forced to SGPR so the
// 21 classifier-weight float4 loads scalarize (s_load_dwordx4).
// Block (0,0) also zero-inits the cross-kernel accumulators (visible to
// k_main via the kernel-boundary release/acquire on the same stream).
__global__ __launch_bounds__(512) void k_corr(const float* __restrict__ fm,
                                              const float* __restrict__ cw) {
    if (blockIdx.x == 0 && blockIdx.y == 0) {
        if (threadIdx.x < 6) g_acc[threadIdx.x] = 0.f;
        if (threadIdx.x == 6) g_ticket = 0u;
    }

    int b = blockIdx.y;
    int lane = threadIdx.x & 63;
    int chunk = __builtin_amdgcn_readfirstlane(threadIdx.x >> 6);  // 0..7, SGPR
    int hw = blockIdx.x * 64 + lane;
    bool valid = hw < HWF;
    const float* fbase = fm + (size_t)b * CFEAT * HWF + (valid ? hw : 0);
    int cbase = chunk * (CFEAT / 8);

    float acc[KCLS];
    #pragma unroll
    for (int k = 0; k < KCLS; ++k) acc[k] = 0.f;
    float nrm = 0.f;

    // unroll-8: 8 outstanding feature loads per wave per iteration
    for (int j = 0; j < CFEAT/8; j += 8) {
        int c = cbase + j;
        float f[8];
        #pragma unroll
        for (int u = 0; u < 8; ++u) f[u] = fbase[(size_t)(c+u)*HWF];
        #pragma unroll
        for (int u = 0; u < 8; ++u) nrm = fmaf(f[u], f[u], nrm);
        #pragma unroll
        for (int k = 0; k < KCLS; ++k) {
            // all-scalar addresses -> s_load_dwordx4
            const float4 w0 = *reinterpret_cast<const float4*>(cw + (size_t)k*CFEAT + c);
            const float4 w1 = *reinterpret_cast<const float4*>(cw + (size_t)k*CFEAT + c + 4);
            acc[k] = fmaf(f[0],w0.x, fmaf(f[1],w0.y, fmaf(f[2],w0.z, fmaf(f[3],w0.w, acc[k]))));
            acc[k] = fmaf(f[4],w1.x, fmaf(f[5],w1.y, fmaf(f[6],w1.z, fmaf(f[7],w1.w, acc[k]))));
        }
    }

    __shared__ float red[KCLS+1][8][64];
    __shared__ float s_wn[KCLS];
    #pragma unroll
    for (int k = 0; k < KCLS; ++k) red[k][chunk][lane] = acc[k];
    red[KCLS][chunk][lane] = nrm;
    __syncthreads();

    // fused weight norms: wave w handles classes w, w+8, w+16 (cw is L2-hot)
    for (int k = chunk; k < KCLS; k += 8) {
        float s = 0.f;
        const float4* row = reinterpret_cast<const float4*>(cw + (size_t)k*CFEAT);
        #pragma unroll
        for (int i = 0; i < CFEAT/4/64; ++i) {
            float4 v4 = row[lane + 64*i];
            s = fmaf(v4.x,v4.x, fmaf(v4.y,v4.y, fmaf(v4.z,v4.z, fmaf(v4.w,v4.w, s))));
        }
        #pragma unroll
        for (int off = 32; off; off >>= 1) s += __shfl_down(s, off, 64);
        if (lane == 0) s_wn[k] = sqrtf(s);
    }
    __syncthreads();

    if (threadIdx.x < 64) {
        int p = lane;
        int hw2 = blockIdx.x * 64 + p;
        if (hw2 < HWF) {
            float n8 = 0.f;
            #pragma unroll
            for (int j = 0; j < 8; ++j) n8 += red[KCLS][j][p];
            float fn = sqrtf(n8);
            float* out = g_corr + (size_t)b * KCLS * HWF + hw2;
            #pragma unroll
            for (int k = 0; k < KCLS; ++k) {
                float d = 0.f;
                #pragma unroll
                for (int j = 0; j < 8; ++j) d += red[k][j][p];
                float den = fmaxf(fn * s_wn[k], EPSC);
                out[(size_t)k * HWF] = 1.f + d / den;
            }
        }
    }
}

// ---------------- kernel C: main pass + global reduce + final loss ------
__global__ __launch_bounds__(256) void k_main(const float* __restrict__ yp,
                                              const int* __restrict__ ycrf,
                                              const int* __restrict__ yret,
                                              float* __restrict__ out) {
    int tid = threadIdx.x;
    int p = blockIdx.x * 256 + tid;
    float a0=0.f, a1=0.f, a2=0.f, a3=0.f, a4=0.f, a5=0.f;
    if (p < NPIX) {
        int b = p / HWI;
        int r = p - b * HWI;
        int h = r / WW;
        int w = r - h * WW;
        int c = ycrf[p];
        bool match = (c == yret[p]);

        const float* ybase = yp + (size_t)b * KCLS * HWI + r;
        float v[KCLS];
        float mx = -1e30f, sum_y = 0.f;
        #pragma unroll
        for (int k = 0; k < KCLS; ++k) {
            v[k] = ybase[(size_t)k * HWI];
            sum_y += v[k];
            mx = fmaxf(mx, v[k]);
        }
        float se = 0.f, yc = 0.f;
        #pragma unroll
        for (int k = 0; k < KCLS; ++k) {
            se += __expf(v[k] - mx);
            yc = (k == c) ? v[k] : yc;
        }
        float lse = __logf(se);
        float logp_c = yc - mx - lse;
        float sum_logp = sum_y - (float)KCLS * (mx + lse);

        // half-pixel bilinear coords, clamp-to-edge (== jax renormalized tri)
        const float S = (float)HF / (float)HH;
        float xf = ((float)w + 0.5f) * S - 0.5f;
        float yf = ((float)h + 0.5f) * S - 0.5f;
        float xg = floorf(xf), yg = floorf(yf);
        float fx = xf - xg, fy = yf - yg;
        int ix0 = (int)xg; if (ix0 < 0) ix0 = 0;
        int iy0 = (int)yg; if (iy0 < 0) iy0 = 0;
        int ix1 = (int)xg + 1; if (ix1 > WF-1) ix1 = WF-1; if (ix1 < 0) ix1 = 0;
        int iy1 = (int)yg + 1; if (iy1 > HF-1) iy1 = HF-1; if (iy1 < 0) iy1 = 0;
        float w00 = (1.f-fx)*(1.f-fy), w01 = fx*(1.f-fy);
        float w10 = (1.f-fx)*fy,       w11 = fx*fy;
        int o00 = iy0*WF+ix0, o01 = iy0*WF+ix1, o10 = iy1*WF+ix0, o11 = iy1*WF+ix1;

        const float* cb = g_corr + (size_t)b * KCLS * HWF;
        float cmax = -1e30f, cstar = 0.f;
        #pragma unroll
        for (int k = 0; k < KCLS; ++k) {
            const float* ck = cb + (size_t)k * HWF;
            float cv = w00*ck[o00] + w01*ck[o01] + w10*ck[o10] + w11*ck[o11];
            cmax = fmaxf(cmax, cv);
            cstar = (k == c) ? cv : cstar;
        }
        float ratio = cstar / cmax;
        float conf = ratio * ratio;
        float mf = match ? 1.f : 0.f;

        a0 = match ? logp_c : 0.f;   // sum match*logp_c
        a1 = mf;                     // cnt
        a2 = conf * sum_logp;        // sum conf*sum_logp
        a3 = mf * conf * logp_c;     // sum m*conf*logp_c
        a4 = conf;                   // sum conf
        a5 = mf * conf;              // sum m*conf
    }

    #pragma unroll
    for (int off = 32; off; off >>= 1) {
        a0 += __shfl_down(a0, off, 64);
        a1 += __shfl_down(a1, off, 64);
        a2 += __shfl_down(a2, off, 64);
        a3 += __shfl_down(a3, off, 64);
        a4 += __shfl_down(a4, off, 64);
        a5 += __shfl_down(a5, off, 64);
    }
    __shared__ float s[4][6];
    int wave = tid >> 6, lane = tid & 63;
    if (lane == 0) {
        s[wave][0]=a0; s[wave][1]=a1; s[wave][2]=a2;
        s[wave][3]=a3; s[wave][4]=a4; s[wave][5]=a5;
    }
    __syncthreads();
    if (tid == 0) {
        float t0 = s[0][0]+s[1][0]+s[2][0]+s[3][0];
        float t1 = s[0][1]+s[1][1]+s[2][1]+s[3][1];
        float t2 = s[0][2]+s[1][2]+s[2][2]+s[3][2];
        float t3 = s[0][3]+s[1][3]+s[2][3]+s[3][3];
        float t4 = s[0][4]+s[1][4]+s[2][4]+s[3][4];
        float t5 = s[0][5]+s[1][5]+s[2][5]+s[3][5];
        atomicAdd(&g_acc[0], t0);
        atomicAdd(&g_acc[1], t1);
        atomicAdd(&g_acc[2], t2);
        atomicAdd(&g_acc[3], t3);
        atomicAdd(&g_acc[4], t4);
        atomicAdd(&g_acc[5], t5);
        __threadfence();
        unsigned old = atomicAdd(&g_ticket, 1u);
        if (old == gridDim.x - 1) {
            // last block: all prior atomics visible via the atomic path
            float A    = atomicAdd(&g_acc[0], 0.f);
            float CNT  = atomicAdd(&g_acc[1], 0.f);
            float Scs  = atomicAdd(&g_acc[2], 0.f);
            float Smcl = atomicAdd(&g_acc[3], 0.f);
            float Sc   = atomicAdd(&g_acc[4], 0.f);
            float Smc  = atomicAdd(&g_acc[5], 0.f);
            float loss_ce  = -A / CNT;
            float numer = Scs - Smcl;
            float denom = (float)KCLS * Sc - Smc;
            float loss_wce = -numer / denom;
            out[0] = loss_ce + loss_wce;
        }
    }
}

extern "C" void kernel_launch(void* const* d_in, const int* in_sizes, int n_in,
                              void* d_out, int out_size, void* d_ws, size_t ws_size,
                              hipStream_t stream) {
    const float* y_pred = (const float*)d_in[0];
    const int*   ycrf   = (const int*)d_in[1];
    const int*   yret   = (const int*)d_in[2];
    const float* fm     = (const float*)d_in[3];
    const float* cw     = (const float*)d_in[4];
    float* out = (float*)d_out;

    k_corr<<<dim3((HWF+63)/64, BATCH), 512, 0, stream>>>(fm, cw);
    k_main<<<NBLK_C, 256, 0, stream>>>(y_pred, ycrf, yret, out);
}